// Round 1
// baseline (948.836 us; speedup 1.0000x reference)
//
#include <hip/hip_runtime.h>
#include <cfloat>

#define NFEAT 256
#define BATCH 4096
#define MTOT  16384   // 128*128 codebook entries
#define NSPLIT 16
#define BM 64
#define BN 64
#define BK 64

// ---------------------------------------------------------------------------
// Kernel 0: squared L2 norm per row. One wave (64 lanes) per row of 256 f32.
// ---------------------------------------------------------------------------
__global__ __launch_bounds__(256) void sq_norm_kernel(const float* __restrict__ src,
                                                      float* __restrict__ dst,
                                                      int nrows) {
    int gid  = blockIdx.x * blockDim.x + threadIdx.x;
    int row  = gid >> 6;
    int lane = threadIdx.x & 63;
    if (row >= nrows) return;
    float4 v = *reinterpret_cast<const float4*>(src + (size_t)row * NFEAT + 4 * lane);
    float s = v.x * v.x + v.y * v.y + v.z * v.z + v.w * v.w;
    #pragma unroll
    for (int off = 32; off > 0; off >>= 1) s += __shfl_down(s, off);
    if (lane == 0) dst[row] = s;
}

// ---------------------------------------------------------------------------
// Kernel 1: fused distance-GEMM + partial argmin.
// Block: 256 threads (16x16), each thread owns a 4x4 micro-tile.
// Tile: BM=64 batch rows x BN=64 codebook entries, K staged in BK=64 chunks.
// Grid: (4096/BM, NSPLIT). Each block scans MTOT/NSPLIT codebook entries and
// writes one (minval, minidx) partial per batch row.
// Score = sqrt(max(a2 + b2 - 2*dot, 0)) to mirror the reference's compare
// values exactly (sqrt compression affects tie resolution).
// ---------------------------------------------------------------------------
__global__ __launch_bounds__(256) void som_kernel(const float* __restrict__ xb,
                                                  const float* __restrict__ w,
                                                  const float* __restrict__ a2,
                                                  const float* __restrict__ b2,
                                                  float* __restrict__ pmin,
                                                  int* __restrict__ pidx) {
    __shared__ __align__(16) float As[BM][BK + 4];   // [m][k] row-major
    __shared__ __align__(16) float Bs[BK][BN + 4];   // [k][n] transposed

    const int t  = threadIdx.x;
    const int tx = t & 15;        // codebook direction (4 cols each)
    const int ty = t >> 4;        // batch direction   (4 rows each)
    const int m0 = blockIdx.x * BM;
    const int nbase = blockIdx.y * (MTOT / NSPLIT);

    float a2r[4];
    #pragma unroll
    for (int i = 0; i < 4; ++i) a2r[i] = a2[m0 + 4 * ty + i];

    float bestv[4];
    int   besti[4];
    #pragma unroll
    for (int i = 0; i < 4; ++i) { bestv[i] = FLT_MAX; besti[i] = 0; }

    for (int nt = 0; nt < (MTOT / NSPLIT) / BN; ++nt) {   // 16 n-tiles
        const int n0 = nbase + nt * BN;
        float acc[4][4];
        #pragma unroll
        for (int i = 0; i < 4; ++i)
            #pragma unroll
            for (int j = 0; j < 4; ++j) acc[i][j] = 0.f;

        for (int kt = 0; kt < NFEAT / BK; ++kt) {         // 4 k-chunks
            const int k0 = kt * BK;
            __syncthreads();   // protect LDS from previous iteration's readers
            #pragma unroll
            for (int i = 0; i < 4; ++i) {
                const int r = (t >> 4) + 16 * i;          // 0..63
                const int kq = t & 15;                    // 0..15 (4 floats each)
                float4 va = *reinterpret_cast<const float4*>(
                    &xb[(size_t)(m0 + r) * NFEAT + k0 + 4 * kq]);
                *reinterpret_cast<float4*>(&As[r][4 * kq]) = va;
                float4 vb = *reinterpret_cast<const float4*>(
                    &w[(size_t)(n0 + r) * NFEAT + k0 + 4 * kq]);
                Bs[4 * kq + 0][r] = vb.x;
                Bs[4 * kq + 1][r] = vb.y;
                Bs[4 * kq + 2][r] = vb.z;
                Bs[4 * kq + 3][r] = vb.w;
            }
            __syncthreads();

            #pragma unroll
            for (int kk = 0; kk < BK; kk += 4) {
                float a[4][4], b[4][4];
                #pragma unroll
                for (int i = 0; i < 4; ++i)
                    *reinterpret_cast<float4*>(a[i]) =
                        *reinterpret_cast<const float4*>(&As[4 * ty + i][kk]);
                #pragma unroll
                for (int p = 0; p < 4; ++p)
                    *reinterpret_cast<float4*>(b[p]) =
                        *reinterpret_cast<const float4*>(&Bs[kk + p][4 * tx]);
                #pragma unroll
                for (int i = 0; i < 4; ++i)
                    #pragma unroll
                    for (int j = 0; j < 4; ++j)
                        acc[i][j] += a[i][0] * b[0][j] + a[i][1] * b[1][j]
                                   + a[i][2] * b[2][j] + a[i][3] * b[3][j];
            }
        }

        // epilogue for this n-tile: score + running argmin
        float b2n[4];
        #pragma unroll
        for (int j = 0; j < 4; ++j) b2n[j] = b2[n0 + 4 * tx + j];
        #pragma unroll
        for (int i = 0; i < 4; ++i) {
            #pragma unroll
            for (int j = 0; j < 4; ++j) {
                float d2 = a2r[i] + b2n[j] - 2.f * acc[i][j];
                float s  = sqrtf(fmaxf(d2, 0.f));
                int idx  = n0 + 4 * tx + j;
                if (s < bestv[i] || (s == bestv[i] && idx < besti[i])) {
                    bestv[i] = s;
                    besti[i] = idx;
                }
            }
        }
    }

    // cross-thread (tx) reduction per batch row via LDS scratch
    __syncthreads();
    float* sv = &As[0][0];                       // 64*16 floats, fits
    int*   si = reinterpret_cast<int*>(&Bs[0][0]);
    #pragma unroll
    for (int i = 0; i < 4; ++i) {
        sv[(4 * ty + i) * 16 + tx] = bestv[i];
        si[(4 * ty + i) * 16 + tx] = besti[i];
    }
    __syncthreads();
    if (t < BM) {
        float bv = FLT_MAX;
        int   bi = 0;
        #pragma unroll
        for (int x = 0; x < 16; ++x) {
            float v = sv[t * 16 + x];
            int  ii = si[t * 16 + x];
            if (v < bv || (v == bv && ii < bi)) { bv = v; bi = ii; }
        }
        pmin[(size_t)(m0 + t) * NSPLIT + blockIdx.y] = bv;
        pidx[(size_t)(m0 + t) * NSPLIT + blockIdx.y] = bi;
    }
}

// ---------------------------------------------------------------------------
// Kernel 2: reduce NSPLIT partials per batch row, emit (row, col) int32.
// ---------------------------------------------------------------------------
__global__ __launch_bounds__(256) void finalize_kernel(const float* __restrict__ pmin,
                                                       const int* __restrict__ pidx,
                                                       int* __restrict__ out) {
    int b = blockIdx.x * blockDim.x + threadIdx.x;
    if (b >= BATCH) return;
    float bv = FLT_MAX;
    int   bi = 0;
    #pragma unroll
    for (int s2 = 0; s2 < NSPLIT; ++s2) {
        float v = pmin[(size_t)b * NSPLIT + s2];
        int  ii = pidx[(size_t)b * NSPLIT + s2];
        if (v < bv || (v == bv && ii < bi)) { bv = v; bi = ii; }
    }
    out[2 * b + 0] = bi >> 7;    // // 128
    out[2 * b + 1] = bi & 127;   // %  128
}

extern "C" void kernel_launch(void* const* d_in, const int* in_sizes, int n_in,
                              void* d_out, int out_size, void* d_ws, size_t ws_size,
                              hipStream_t stream) {
    const float* xb = (const float*)d_in[0];   // (4096, 256)
    const float* w  = (const float*)d_in[1];   // (128,128,256) -> (16384,256)
    int* out = (int*)d_out;                    // (4096, 2) int32

    // workspace carving: a2 | b2 | pmin | pidx
    float* a2   = (float*)d_ws;                      // 4096 f
    float* b2   = a2 + BATCH;                        // 16384 f
    float* pmin = b2 + MTOT;                         // 4096*16 f
    int*   pidx = (int*)(pmin + (size_t)BATCH * NSPLIT);

    sq_norm_kernel<<<dim3((MTOT * 64) / 256), 256, 0, stream>>>(w, b2, MTOT);
    sq_norm_kernel<<<dim3((BATCH * 64) / 256), 256, 0, stream>>>(xb, a2, BATCH);

    dim3 grid(BATCH / BM, NSPLIT);
    som_kernel<<<grid, 256, 0, stream>>>(xb, w, a2, b2, pmin, pidx);

    finalize_kernel<<<BATCH / 256, 256, 0, stream>>>(pmin, pidx, out);
}

// Round 2
// 221.469 us; speedup vs baseline: 4.2843x; 4.2843x over previous
//
#include <hip/hip_runtime.h>
#include <cfloat>

#define NFEAT 256
#define BATCH 4096
#define MTOT  16384
#define NCHUNK 256            // 16384 / 64-col chunks
#define MARGIN 1.0f

typedef __attribute__((ext_vector_type(8))) short bf16x8;
typedef __attribute__((ext_vector_type(4))) float f32x4;

// ---------------------------------------------------------------------------
// fp32 -> bf16 (RNE) conversion, 8 elems/thread
// ---------------------------------------------------------------------------
__device__ __forceinline__ unsigned bf16pack(float a, float b) {
    unsigned ua = __float_as_uint(a), ub = __float_as_uint(b);
    unsigned ra = (ua + 0x7fffu + ((ua >> 16) & 1u)) >> 16;
    unsigned rb = (ub + 0x7fffu + ((ub >> 16) & 1u)) >> 16;
    return ra | (rb << 16);
}

__global__ __launch_bounds__(256) void cvt_bf16_kernel(const float* __restrict__ src,
                                                       unsigned* __restrict__ dst, int n8) {
    int i = blockIdx.x * blockDim.x + threadIdx.x;
    if (i >= n8) return;
    const float4* s = (const float4*)src;
    float4 v0 = s[2 * i], v1 = s[2 * i + 1];
    uint4 o;
    o.x = bf16pack(v0.x, v0.y);
    o.y = bf16pack(v0.z, v0.w);
    o.z = bf16pack(v1.x, v1.y);
    o.w = bf16pack(v1.z, v1.w);
    ((uint4*)dst)[i] = o;
}

// ---------------------------------------------------------------------------
// squared L2 norm per row (one wave per row of 256 f32)
// ---------------------------------------------------------------------------
__global__ __launch_bounds__(256) void sq_norm_kernel(const float* __restrict__ src,
                                                      float* __restrict__ dst, int nrows) {
    int gid  = blockIdx.x * blockDim.x + threadIdx.x;
    int row  = gid >> 6;
    int lane = threadIdx.x & 63;
    if (row >= nrows) return;
    float4 v = *reinterpret_cast<const float4*>(src + (size_t)row * NFEAT + 4 * lane);
    float s = v.x * v.x + v.y * v.y + v.z * v.z + v.w * v.w;
    #pragma unroll
    for (int off = 32; off > 0; off >>= 1) s += __shfl_down(s, off);
    if (lane == 0) dst[row] = s;
}

// ---------------------------------------------------------------------------
// MFMA bf16 distance-GEMM + per-row top-2 per 64-col chunk.
// Block 256 thr = 4 waves (2x2), tile 128x128, BK=128, LDS 64 KB (2 blk/CU).
// Approx score s' = b2[c] - 2*dot (a2 is row-constant; ordering preserved).
// LDS XOR-swizzle byte^=((row&7)<<4); inverse pre-applied to global source
// since global_load_lds writes linearly (T21 both-sides rule).
// ---------------------------------------------------------------------------
__global__ __launch_bounds__(256, 2) void som_mfma_kernel(
        const unsigned short* __restrict__ Abf, const unsigned short* __restrict__ Bbf,
        const float* __restrict__ b2, float2* __restrict__ part) {
    __shared__ char smem[65536];          // A [128][128]bf16 | B [128][128]bf16

    const int t = threadIdx.x;
    const int l = t & 63;
    const int wid = t >> 6;
    const int wr = wid >> 1, wc = wid & 1;

    // XCD-chunked swizzle: 4096 blocks = 8 xcd * (32 m * 16 n)
    int b   = blockIdx.x;
    int xcd = b & 7, c = b >> 3;
    int n_tile = xcd * 16 + (c & 15);     // 0..127
    int m_tile = c >> 4;                  // 0..31
    const int m0 = m_tile * 128, n0 = n_tile * 128;

    f32x4 acc[4][4];
    #pragma unroll
    for (int m = 0; m < 4; ++m)
        #pragma unroll
        for (int n = 0; n < 4; ++n) acc[m][n] = {0.f, 0.f, 0.f, 0.f};

    const char* gA = (const char*)Abf + (size_t)m0 * 512;   // 512 B per 256-feat row
    const char* gB = (const char*)Bbf + (size_t)n0 * 512;

    #pragma unroll
    for (int kt = 0; kt < 2; ++kt) {
        __syncthreads();   // previous readers done
        // ---- stage 32 KB A + 32 KB B, swizzled source, linear LDS dest ----
        #pragma unroll
        for (int i = 0; i < 8; ++i) {
            int d    = i * 4096 + t * 16;                    // LDS byte offset
            int grow = d >> 8;                               // tile row (256 B rows)
            int srow = (d & 255) ^ (((d >> 8) & 7) << 4);    // swizzled in-row byte
            const char* ga = gA + (size_t)grow * 512 + kt * 256 + srow;
            const char* gb = gB + (size_t)grow * 512 + kt * 256 + srow;
            __builtin_amdgcn_global_load_lds(
                (const __attribute__((address_space(1))) void*)ga,
                (__attribute__((address_space(3))) void*)(smem + d), 16, 0, 0);
            __builtin_amdgcn_global_load_lds(
                (const __attribute__((address_space(1))) void*)gb,
                (__attribute__((address_space(3))) void*)(smem + 32768 + d), 16, 0, 0);
        }
        __syncthreads();   // drains vmcnt(0)

        // ---- 4 K-steps of K=32 ----
        #pragma unroll
        for (int kk = 0; kk < 4; ++kk) {
            bf16x8 af[4], bfr[4];
            #pragma unroll
            for (int m = 0; m < 4; ++m) {
                int row_l = wr * 64 + 16 * m + (l & 15);
                int off = (row_l * 256 + kk * 64 + (l >> 4) * 16) ^ ((l & 7) << 4);
                af[m] = *(const bf16x8*)(smem + off);
            }
            #pragma unroll
            for (int n = 0; n < 4; ++n) {
                int col_l = wc * 64 + 16 * n + (l & 15);
                int off = 32768 + ((col_l * 256 + kk * 64 + (l >> 4) * 16) ^ ((l & 7) << 4));
                bfr[n] = *(const bf16x8*)(smem + off);
            }
            #pragma unroll
            for (int m = 0; m < 4; ++m)
                #pragma unroll
                for (int n = 0; n < 4; ++n)
                    acc[m][n] = __builtin_amdgcn_mfma_f32_16x16x32_bf16(
                        af[m], bfr[n], acc[m][n], 0, 0, 0);
        }
    }

    // ---- epilogue: per-row top-2 over this wave's 64 columns ----
    float b2r[4];
    int   colg[4];
    #pragma unroll
    for (int n = 0; n < 4; ++n) {
        colg[n] = n0 + wc * 64 + 16 * n + (l & 15);
        b2r[n]  = b2[colg[n]];
    }
    const int chunk = n_tile * 2 + wc;

    #pragma unroll
    for (int m = 0; m < 4; ++m) {
        #pragma unroll
        for (int j = 0; j < 4; ++j) {
            float v0 = FLT_MAX, v1 = FLT_MAX;
            int   i0 = 0x7fffffff, i1 = 0x7fffffff;
            #pragma unroll
            for (int n = 0; n < 4; ++n) {
                float v = b2r[n] - 2.f * acc[m][n][j];
                int   ix = colg[n];
                if (v < v0 || (v == v0 && ix < i0)) { v1 = v0; i1 = i0; v0 = v; i0 = ix; }
                else if (v < v1 || (v == v1 && ix < i1)) { v1 = v; i1 = ix; }
            }
            #pragma unroll
            for (int off = 1; off < 16; off <<= 1) {
                float ov0 = __shfl_xor(v0, off), ov1 = __shfl_xor(v1, off);
                int   oi0 = __shfl_xor(i0, off), oi1 = __shfl_xor(i1, off);
                if (ov0 < v0 || (ov0 == v0 && oi0 < i0)) { v1 = v0; i1 = i0; v0 = ov0; i0 = oi0; }
                else if (ov0 < v1 || (ov0 == v1 && oi0 < i1)) { v1 = ov0; i1 = oi0; }
                if (ov1 < v0 || (ov1 == v0 && oi1 < i0)) { v1 = v0; i1 = i0; v0 = ov1; i0 = oi1; }
                else if (ov1 < v1 || (ov1 == v1 && oi1 < i1)) { v1 = ov1; i1 = oi1; }
            }
            if ((l & 15) == 0) {
                int row_g = m0 + wr * 64 + 16 * m + (l >> 4) * 4 + j;
                size_t base = ((size_t)row_g * NCHUNK + chunk) * 2;
                part[base]     = make_float2(v0, __int_as_float(i0));
                part[base + 1] = make_float2(v1, __int_as_float(i1));
            }
        }
    }
}

// ---------------------------------------------------------------------------
// Refine: per row, approx-min over 512 partials, exact fp32 recompute of all
// candidates within MARGIN, lexicographic (sqrt-dist, index) argmin.
// ---------------------------------------------------------------------------
__global__ __launch_bounds__(256) void refine_kernel(
        const float* __restrict__ xb, const float* __restrict__ w,
        const float* __restrict__ a2, const float* __restrict__ b2,
        const float2* __restrict__ part, int* __restrict__ out) {
    __shared__ float svmin[4];
    __shared__ unsigned long long skey[4];
    const int row = blockIdx.x, t = threadIdx.x;

    const float2* pr = part + (size_t)row * (NCHUNK * 2);
    float2 e0 = pr[t], e1 = pr[t + 256];

    float vmin = fminf(e0.x, e1.x);
    #pragma unroll
    for (int off = 32; off > 0; off >>= 1) vmin = fminf(vmin, __shfl_xor(vmin, off));
    if ((t & 63) == 0) svmin[t >> 6] = vmin;
    __syncthreads();
    vmin = fminf(fminf(svmin[0], svmin[1]), fminf(svmin[2], svmin[3]));
    const float cut = vmin + MARGIN;

    const float a2r = a2[row];
    const float4* xr = (const float4*)(xb + (size_t)row * NFEAT);
    unsigned long long key = ~0ull;
    #pragma unroll
    for (int e = 0; e < 2; ++e) {
        float2 en = e ? e1 : e0;
        if (en.x <= cut) {
            int idx = __float_as_int(en.y);
            const float4* wr_ = (const float4*)(w + (size_t)idx * NFEAT);
            float dot = 0.f;
            #pragma unroll 8
            for (int q = 0; q < NFEAT / 4; ++q) {
                float4 xv = xr[q], wv = wr_[q];
                dot += xv.x * wv.x + xv.y * wv.y + xv.z * wv.z + xv.w * wv.w;
            }
            float d2 = a2r + b2[idx] - 2.f * dot;
            float s  = sqrtf(fmaxf(d2, 0.f));
            unsigned long long k =
                ((unsigned long long)__float_as_uint(s) << 32) | (unsigned)idx;
            key = k < key ? k : key;
        }
    }
    #pragma unroll
    for (int off = 32; off > 0; off >>= 1) {
        unsigned long long o = __shfl_xor(key, off);
        key = o < key ? o : key;
    }
    if ((t & 63) == 0) skey[t >> 6] = key;
    __syncthreads();
    if (t == 0) {
        unsigned long long k = skey[0];
        #pragma unroll
        for (int i = 1; i < 4; ++i) k = skey[i] < k ? skey[i] : k;
        int idx = (int)(k & 0xffffffffu);
        out[2 * row]     = idx >> 7;
        out[2 * row + 1] = idx & 127;
    }
}

extern "C" void kernel_launch(void* const* d_in, const int* in_sizes, int n_in,
                              void* d_out, int out_size, void* d_ws, size_t ws_size,
                              hipStream_t stream) {
    const float* xb = (const float*)d_in[0];   // (4096, 256)
    const float* w  = (const float*)d_in[1];   // (16384, 256)
    int* out = (int*)d_out;

    char* ws = (char*)d_ws;
    unsigned short* Abf = (unsigned short*)ws;                        // 2 MB
    unsigned short* Bbf = (unsigned short*)(ws + (2u << 20));         // 8 MB
    float*  a2   = (float*)(ws + (10u << 20));                        // 16 KB
    float*  b2   = (float*)(ws + (10u << 20) + (64u << 10));          // 64 KB
    float2* part = (float2*)(ws + (10u << 20) + (128u << 10));        // 16 MB

    cvt_bf16_kernel<<<(BATCH * NFEAT / 8) / 256, 256, 0, stream>>>(xb, (unsigned*)Abf,
                                                                   BATCH * NFEAT / 8);
    cvt_bf16_kernel<<<(MTOT * NFEAT / 8) / 256, 256, 0, stream>>>(w, (unsigned*)Bbf,
                                                                  MTOT * NFEAT / 8);
    sq_norm_kernel<<<(MTOT * 64) / 256, 256, 0, stream>>>(w, b2, MTOT);
    sq_norm_kernel<<<(BATCH * 64) / 256, 256, 0, stream>>>(xb, a2, BATCH);

    som_mfma_kernel<<<(BATCH / 128) * (MTOT / 128), 256, 0, stream>>>(Abf, Bbf, b2, part);

    refine_kernel<<<BATCH, 256, 0, stream>>>(xb, w, a2, b2, part, out);
}

// Round 3
// 72.830 us; speedup vs baseline: 13.0280x; 3.0409x over previous
//
#include <hip/hip_runtime.h>
#include <cfloat>

#define NFEAT 256
#define BATCH 4096
#define MTOT  16384
#define NSTRIP 16
#define UMARGIN 0.75f          // u-space margin (score space = 2x)

typedef __attribute__((ext_vector_type(8))) short bf16x8;
typedef __attribute__((ext_vector_type(4))) float f32x4;

__device__ __forceinline__ unsigned bf16pack(float a, float b) {
    unsigned ua = __float_as_uint(a), ub = __float_as_uint(b);
    unsigned ra = (ua + 0x7fffu + ((ua >> 16) & 1u)) >> 16;
    unsigned rb = (ub + 0x7fffu + ((ub >> 16) & 1u)) >> 16;
    return ra | (rb << 16);
}

// ---------------------------------------------------------------------------
// Prep: fused fp32->bf16 convert + squared-norm. One wave per 256-feat row.
// ---------------------------------------------------------------------------
__global__ __launch_bounds__(256) void prep_kernel(const float* __restrict__ src,
                                                   uint2* __restrict__ dstbf,
                                                   float* __restrict__ norm, int nrows) {
    int gid  = blockIdx.x * blockDim.x + threadIdx.x;
    int row  = gid >> 6;
    int lane = threadIdx.x & 63;
    if (row >= nrows) return;
    float4 v = *reinterpret_cast<const float4*>(src + (size_t)row * NFEAT + 4 * lane);
    dstbf[(size_t)row * 64 + lane] = make_uint2(bf16pack(v.x, v.y), bf16pack(v.z, v.w));
    float s = v.x * v.x + v.y * v.y + v.z * v.z + v.w * v.w;
    #pragma unroll
    for (int off = 32; off > 0; off >>= 1) s += __shfl_down(s, off);
    if (lane == 0) norm[row] = s;
}

// ---------------------------------------------------------------------------
// Main: MFMA distance-GEMM, acc initialized to -b2/2 so min-dist == max-acc.
// Per-lane running top-2 (fmax + fmed3) with 5-bit candidate id packed into
// the low mantissa bits (v_and_or_b32). Block sweeps 8 n-tiles (one strip of
// 1024 cols); no cross-lane merge — every lane stores its top-2 at the end.
// LDS 32 KB (BK=64 double halves of A,B), XOR-swizzled (T2/T21 both-sides).
// ---------------------------------------------------------------------------
__global__ __launch_bounds__(256, 2) void som_mfma_kernel(
        const unsigned short* __restrict__ Abf, const unsigned short* __restrict__ Bbf,
        const float* __restrict__ b2, float2* __restrict__ part) {
    __shared__ char smem[32768];           // A half 16 KB | B half 16 KB

    const int t = threadIdx.x, l = t & 63;
    const int wid = t >> 6, wr = wid >> 1, wc = wid & 1;

    // 512 blocks = 8 xcd x (32 m x 2 strips); XCD owns 2 strips (L2 locality)
    int bid = blockIdx.x;
    int xcd = bid & 7, cc = bid >> 3;
    int strip  = xcd * 2 + (cc >> 5);      // 0..15
    int m_tile = cc & 31;                  // 0..31
    const int m0  = m_tile * 128;
    const int ns0 = strip * 1024;

    // staging source pointers (pre-swizzled global, linear LDS dest)
    const int srow = (((t & 7) ^ ((t >> 3) & 7)) << 4);
    const char* pA = (const char*)Abf + (size_t)(m0 + (t >> 3)) * 512 + srow;
    const char* pB = (const char*)Bbf + (size_t)(ns0 + (t >> 3)) * 512 + srow;
    char* ldsA = smem + t * 16;
    char* ldsB = smem + 16384 + t * 16;

    float r0[4][4], r1[4][4];
    #pragma unroll
    for (int m = 0; m < 4; ++m)
        #pragma unroll
        for (int j = 0; j < 4; ++j) { r0[m][j] = -FLT_MAX; r1[m][j] = -FLT_MAX; }

    const unsigned mask = 0xFFFFFFE0u;     // clear low 5 mantissa bits

    for (int nt = 0; nt < 8; ++nt) {
        // acc init: -b2/2 broadcast over the 4 j-slots (col = lane&15 for all j)
        const int colbase = ns0 + nt * 128 + wc * 64 + (l & 15);
        float b2h[4];
        #pragma unroll
        for (int n = 0; n < 4; ++n) b2h[n] = -0.5f * b2[colbase + 16 * n];
        f32x4 acc[4][4];
        #pragma unroll
        for (int m = 0; m < 4; ++m)
            #pragma unroll
            for (int n = 0; n < 4; ++n)
                acc[m][n] = (f32x4){b2h[n], b2h[n], b2h[n], b2h[n]};

        #pragma unroll
        for (int kt = 0; kt < 4; ++kt) {
            __syncthreads();               // prev readers done
            #pragma unroll
            for (int i = 0; i < 4; ++i) {
                __builtin_amdgcn_global_load_lds(
                    (const __attribute__((address_space(1))) void*)(pA + i * 16384 + kt * 128),
                    (__attribute__((address_space(3))) void*)(ldsA + i * 4096), 16, 0, 0);
                __builtin_amdgcn_global_load_lds(
                    (const __attribute__((address_space(1))) void*)(pB + (size_t)nt * 65536 + i * 16384 + kt * 128),
                    (__attribute__((address_space(3))) void*)(ldsB + i * 4096), 16, 0, 0);
            }
            __syncthreads();               // vmcnt(0) drained by compiler

            #pragma unroll
            for (int kk = 0; kk < 2; ++kk) {
                const int swz = (kk * 64 + (l >> 4) * 16) ^ ((l & 7) << 4);
                bf16x8 af[4], bfr[4];
                #pragma unroll
                for (int m = 0; m < 4; ++m) {
                    int row_l = wr * 64 + 16 * m + (l & 15);
                    af[m] = *(const bf16x8*)(smem + row_l * 128 + swz);
                }
                #pragma unroll
                for (int n = 0; n < 4; ++n) {
                    int col_l = wc * 64 + 16 * n + (l & 15);
                    bfr[n] = *(const bf16x8*)(smem + 16384 + col_l * 128 + swz);
                }
                #pragma unroll
                for (int m = 0; m < 4; ++m)
                    #pragma unroll
                    for (int n = 0; n < 4; ++n)
                        acc[m][n] = __builtin_amdgcn_mfma_f32_16x16x32_bf16(
                            af[m], bfr[n], acc[m][n], 0, 0, 0);
            }
        }

        // epilogue: 3 VALU/element (and_or pack, fmax, fmed3)
        #pragma unroll
        for (int n = 0; n < 4; ++n) {
            const unsigned idn = (unsigned)(nt * 4 + n);
            #pragma unroll
            for (int m = 0; m < 4; ++m) {
                #pragma unroll
                for (int j = 0; j < 4; ++j) {
                    float p = __uint_as_float((__float_as_uint(acc[m][n][j]) & mask) | idn);
                    float nr1 = __builtin_amdgcn_fmed3f(r0[m][j], r1[m][j], p);
                    r0[m][j] = fmaxf(r0[m][j], p);
                    r1[m][j] = nr1;
                }
            }
        }
    }

    // store per-lane top-2: part[row][strip][slot] (slot = wc*16 + lane-col)
    const int slot = wc * 16 + (l & 15);
    #pragma unroll
    for (int m = 0; m < 4; ++m)
        #pragma unroll
        for (int j = 0; j < 4; ++j) {
            int rowg = m0 + wr * 64 + 16 * m + (l >> 4) * 4 + j;
            part[((size_t)rowg * NSTRIP + strip) * 32 + slot] =
                make_float2(r0[m][j], r1[m][j]);
        }
}

// ---------------------------------------------------------------------------
// Refine: per row scan 1024 packed candidates, exact fp32+sqrt recompute of
// those within margin of the approx best, lexicographic (dist, idx) argmin.
// ---------------------------------------------------------------------------
__global__ __launch_bounds__(256) void refine_kernel(
        const float* __restrict__ xb, const float* __restrict__ w,
        const float* __restrict__ a2, const float* __restrict__ b2,
        const float* __restrict__ part, int* __restrict__ out) {
    __shared__ float sumax[4];
    __shared__ unsigned long long skey[4];
    const int row = blockIdx.x, t = threadIdx.x;

    const float4 v4 = ((const float4*)(part + (size_t)row * 1024))[t];
    float um = fmaxf(fmaxf(v4.x, v4.y), fmaxf(v4.z, v4.w));
    #pragma unroll
    for (int off = 32; off > 0; off >>= 1) um = fmaxf(um, __shfl_xor(um, off));
    if ((t & 63) == 0) sumax[t >> 6] = um;
    __syncthreads();
    um = fmaxf(fmaxf(sumax[0], sumax[1]), fmaxf(sumax[2], sumax[3]));
    const float cut = um - UMARGIN;

    const float a2r = a2[row];
    const float4* xr = (const float4*)(xb + (size_t)row * NFEAT);
    float uq[4] = {v4.x, v4.y, v4.z, v4.w};
    unsigned long long key = ~0ull;
    #pragma unroll
    for (int q = 0; q < 4; ++q) {
        if (uq[q] >= cut) {
            int f = 4 * t + q;
            unsigned low5 = __float_as_uint(uq[q]) & 31u;
            int st   = f >> 6;              // 64 floats per strip
            int slot = (f >> 1) & 31;
            int col  = st * 1024 + (int)(low5 >> 2) * 128 + (slot >> 4) * 64
                     + (int)(low5 & 3) * 16 + (slot & 15);
            const float4* wr_ = (const float4*)(w + (size_t)col * NFEAT);
            float dot = 0.f;
            #pragma unroll 8
            for (int k = 0; k < NFEAT / 4; ++k) {
                float4 xv = xr[k], wv = wr_[k];
                dot += xv.x * wv.x + xv.y * wv.y + xv.z * wv.z + xv.w * wv.w;
            }
            float d2 = a2r + b2[col] - 2.f * dot;
            float s  = sqrtf(fmaxf(d2, 0.f));
            unsigned long long kk =
                ((unsigned long long)__float_as_uint(s) << 32) | (unsigned)col;
            key = kk < key ? kk : key;
        }
    }
    #pragma unroll
    for (int off = 32; off > 0; off >>= 1) {
        unsigned long long o = __shfl_xor(key, off);
        key = o < key ? o : key;
    }
    if ((t & 63) == 0) skey[t >> 6] = key;
    __syncthreads();
    if (t == 0) {
        unsigned long long k = skey[0];
        #pragma unroll
        for (int i = 1; i < 4; ++i) k = skey[i] < k ? skey[i] : k;
        int idx = (int)(k & 0xffffffffu);
        out[2 * row]     = idx >> 7;
        out[2 * row + 1] = idx & 127;
    }
}

extern "C" void kernel_launch(void* const* d_in, const int* in_sizes, int n_in,
                              void* d_out, int out_size, void* d_ws, size_t ws_size,
                              hipStream_t stream) {
    const float* xb = (const float*)d_in[0];   // (4096, 256)
    const float* w  = (const float*)d_in[1];   // (16384, 256)
    int* out = (int*)d_out;

    char* ws = (char*)d_ws;
    unsigned short* Abf = (unsigned short*)ws;                 // 2 MB
    unsigned short* Bbf = (unsigned short*)(ws + (2u << 20));  // 8 MB
    float* a2   = (float*)(ws + (10u << 20));                  // 16 KB
    float* b2   = (float*)(ws + (10u << 20) + (64u << 10));    // 64 KB
    float* part = (float*)(ws + (10u << 20) + (128u << 10));   // 16 MB

    prep_kernel<<<(MTOT * 64) / 256, 256, 0, stream>>>(w, (uint2*)Bbf, b2, MTOT);
    prep_kernel<<<(BATCH * 64) / 256, 256, 0, stream>>>(xb, (uint2*)Abf, a2, BATCH);

    som_mfma_kernel<<<512, 256, 0, stream>>>(Abf, Bbf, b2, (float2*)part);

    refine_kernel<<<BATCH, 256, 0, stream>>>(xb, w, a2, b2, part, out);
}